// Round 9
// baseline (674.540 us; speedup 1.0000x reference)
//
#include <hip/hip_runtime.h>
#include <hip/hip_bf16.h>
#include <cstddef>

// Problem constants
// B=8, T=256, U=64, D_ENC=D_DEC=J=512, V=1024
// M = B*T*U = 131072, bt-rows = 2048, dec rows = 512

typedef __attribute__((ext_vector_type(8))) short bf16x8;
typedef __attribute__((ext_vector_type(4))) float f32x4;

__device__ __forceinline__ unsigned short f2bf(float f) {
  union { float f; unsigned u; } v; v.f = f;
  unsigned r = v.u + 0x7fffu + ((v.u >> 16) & 1u);   // RNE
  return (unsigned short)(r >> 16);
}

__device__ __forceinline__ float fast_tanh(float x) {
  // tanh(x) = 1 - 2/(exp(2x)+1); robust at +-inf (exp->inf => 1, exp->0 => -1)
  float ex = __expf(2.0f * x);
  return 1.0f - 2.0f * __builtin_amdgcn_rcpf(ex + 1.0f);
}

// ---------------------------------------------------------------------------
// Kernel 1: convert W_out (1024x512 f32) to bf16, packed in MFMA B-fragment
// order: Wf[((ni*16 + ks)*64 + lane)*8 + i] = bf16(W_out[v][k])
//   v = ni*16 + (lane&15), k = ks*32 + (lane>>4)*8 + i
// so the main kernel's B-fragment load is a fully coalesced 16B/lane read.
// ---------------------------------------------------------------------------
__global__ __launch_bounds__(256) void pack_wout(const float* __restrict__ W,
                                                 short* __restrict__ Wf) {
  int gid = blockIdx.x * 256 + threadIdx.x;   // 0..65535
  int lane = gid & 63;
  int ks   = (gid >> 6) & 15;
  int ni   = gid >> 10;                       // 0..63
  int v = ni * 16 + (lane & 15);
  int k = ks * 32 + (lane >> 4) * 8;
  const float4* wp = (const float4*)(W + (size_t)v * 512 + k);
  float4 w0 = wp[0], w1 = wp[1];
  bf16x8 o;
  o[0] = (short)f2bf(w0.x); o[1] = (short)f2bf(w0.y);
  o[2] = (short)f2bf(w0.z); o[3] = (short)f2bf(w0.w);
  o[4] = (short)f2bf(w1.x); o[5] = (short)f2bf(w1.y);
  o[6] = (short)f2bf(w1.z); o[7] = (short)f2bf(w1.w);
  *(bf16x8*)(Wf + (size_t)gid * 8) = o;
}

// ---------------------------------------------------------------------------
// Kernel 2: fp32 projection GEMM  Out[m][n] = sum_k H[m][k]*W[n][k] (+bias[n])
// K = 512 fixed. Block tile 64x64, 256 threads, per-thread 4x4, BK=16.
// ---------------------------------------------------------------------------
__global__ __launch_bounds__(256) void proj_gemm(const float* __restrict__ H,
                                                 const float* __restrict__ W,
                                                 const float* __restrict__ bias,
                                                 float* __restrict__ Out,
                                                 int hasBias) {
  __shared__ float As[16][68];
  __shared__ float Bs[16][68];
  const int m0 = blockIdx.x * 64, n0 = blockIdx.y * 64;
  const int tid = threadIdx.x;
  const int tr = tid >> 4, tc = tid & 15;   // 16x16 thread grid, 4x4 each
  const int lr = tid >> 2;                  // staging row 0..63
  const int lk = (tid & 3) * 4;             // staging k offset 0,4,8,12

  float acc[4][4];
#pragma unroll
  for (int i = 0; i < 4; ++i)
#pragma unroll
    for (int j = 0; j < 4; ++j) acc[i][j] = 0.0f;

  for (int k0 = 0; k0 < 512; k0 += 16) {
    float4 av = *(const float4*)(H + (size_t)(m0 + lr) * 512 + k0 + lk);
    float4 bv = *(const float4*)(W + (size_t)(n0 + lr) * 512 + k0 + lk);
    __syncthreads();
    As[lk + 0][lr] = av.x; As[lk + 1][lr] = av.y;
    As[lk + 2][lr] = av.z; As[lk + 3][lr] = av.w;
    Bs[lk + 0][lr] = bv.x; Bs[lk + 1][lr] = bv.y;
    Bs[lk + 2][lr] = bv.z; Bs[lk + 3][lr] = bv.w;
    __syncthreads();
#pragma unroll
    for (int k = 0; k < 16; ++k) {
      float4 a = *(const float4*)(&As[k][tr * 4]);
      float4 b = *(const float4*)(&Bs[k][tc * 4]);
      float a4[4] = {a.x, a.y, a.z, a.w};
      float b4[4] = {b.x, b.y, b.z, b.w};
#pragma unroll
      for (int i = 0; i < 4; ++i)
#pragma unroll
        for (int j = 0; j < 4; ++j) acc[i][j] = fmaf(a4[i], b4[j], acc[i][j]);
    }
  }
#pragma unroll
  for (int j = 0; j < 4; ++j) {
    float bj = hasBias ? bias[n0 + tc * 4 + j] : 0.0f;
#pragma unroll
    for (int i = 0; i < 4; ++i)
      Out[(size_t)(m0 + tr * 4 + i) * 512 + (n0 + tc * 4 + j)] = acc[i][j] + bj;
  }
}

// ---------------------------------------------------------------------------
// Kernel 3: fused joint: per block (one bt = b*T+t):
//  phase 1: z[u][j] = tanh(E[bt][j] + D[b*64+u][j]) -> LDS bf16, XOR-swizzled
//  phase 2: out[bt*64+u][v] = z @ W_out^T + b_out, bf16 MFMA 16x16x32
// 256 threads = 4 waves; wave w covers v in [w*256, w*256+256), n-chunk 64.
// ---------------------------------------------------------------------------
__global__ __launch_bounds__(256, 2) void joint_main(
    const float* __restrict__ E,        // [2048][512]
    const float* __restrict__ D,        // [512][512]
    const short* __restrict__ Wf,       // packed bf16 frags [64][16][64][8]
    const float* __restrict__ b_out,    // [1024]
    float* __restrict__ out)            // [131072][1024]
{
  __shared__ __align__(16) char zs[64 * 1024];   // 64 rows x 512 bf16 = 64KB
  const int tid = threadIdx.x;
  const int bt = blockIdx.x;         // 0..2047
  const int b  = bt >> 8;            // T = 256

  // ---- phase 1: build z tile ----
  {
    const int jg = tid & 63;         // j-group: 8 floats at j = jg*8
    const int u0 = tid >> 6;         // wave id: starting u
    const float* erow = E + (size_t)bt * 512 + jg * 8;
    float4 e0 = *(const float4*)(erow);
    float4 e1 = *(const float4*)(erow + 4);
    float er[8] = {e0.x, e0.y, e0.z, e0.w, e1.x, e1.y, e1.z, e1.w};
    const float* dbase = D + (size_t)(b * 64) * 512 + jg * 8;
#pragma unroll 4
    for (int it = 0; it < 16; ++it) {
      int u = it * 4 + u0;
      const float* dr = dbase + (size_t)u * 512;
      float4 d0 = *(const float4*)(dr);
      float4 d1 = *(const float4*)(dr + 4);
      float dv[8] = {d0.x, d0.y, d0.z, d0.w, d1.x, d1.y, d1.z, d1.w};
      bf16x8 pk;
#pragma unroll
      for (int i = 0; i < 8; ++i)
        pk[i] = (short)f2bf(fast_tanh(er[i] + dv[i]));
      int bcol = (jg * 16) ^ ((u & 7) << 4);     // G4 XOR swizzle
      *(bf16x8*)(zs + (size_t)u * 1024 + bcol) = pk;
    }
  }
  __syncthreads();

  // ---- phase 2: GEMM ----
  const int wave = tid >> 6, lane = tid & 63;
  const int lr = lane & 15;        // row (A) / col (B/C) selector
  const int kg = lane >> 4;        // k-group

  for (int c = 0; c < 4; ++c) {
    const int nb = wave * 256 + c * 64;          // chunk base v
    f32x4 acc[4][4];
#pragma unroll
    for (int mi = 0; mi < 4; ++mi)
#pragma unroll
      for (int nj = 0; nj < 4; ++nj)
        acc[mi][nj] = (f32x4){0.f, 0.f, 0.f, 0.f};

#pragma unroll 4
    for (int ks = 0; ks < 16; ++ks) {
      bf16x8 a[4];
#pragma unroll
      for (int mi = 0; mi < 4; ++mi) {
        int row = mi * 16 + lr;
        int bcol = (ks * 64 + kg * 16) ^ ((row & 7) << 4);
        a[mi] = *(const bf16x8*)(zs + (size_t)row * 1024 + bcol);
      }
      bf16x8 bb[4];
#pragma unroll
      for (int nj = 0; nj < 4; ++nj) {
        int fi = (nb >> 4) + nj;                 // global n-frag index 0..63
        bb[nj] = *(const bf16x8*)(Wf + (size_t)((fi * 16 + ks) * 64 + lane) * 8);
      }
#pragma unroll
      for (int mi = 0; mi < 4; ++mi)
#pragma unroll
        for (int nj = 0; nj < 4; ++nj)
          acc[mi][nj] = __builtin_amdgcn_mfma_f32_16x16x32_bf16(
              a[mi], bb[nj], acc[mi][nj], 0, 0, 0);
    }

    // epilogue: C/D layout col = lane&15 (v), row = kg*4 + r (m)
#pragma unroll
    for (int nj = 0; nj < 4; ++nj) {
      float bias = b_out[nb + nj * 16 + lr];
#pragma unroll
      for (int mi = 0; mi < 4; ++mi) {
        float* op = out + (size_t)(bt * 64 + mi * 16 + kg * 4) * 1024
                        + (nb + nj * 16 + lr);
#pragma unroll
        for (int r = 0; r < 4; ++r)
          __builtin_nontemporal_store(acc[mi][nj][r] + bias, op + (size_t)r * 1024);
      }
    }
  }
}

// ---------------------------------------------------------------------------
extern "C" void kernel_launch(void* const* d_in, const int* in_sizes, int n_in,
                              void* d_out, int out_size, void* d_ws, size_t ws_size,
                              hipStream_t stream) {
  const float* h_enc = (const float*)d_in[0];   // (8,256,1,512) -> [2048][512]
  const float* h_dec = (const float*)d_in[1];   // (8,1,64,512)  -> [512][512]
  const float* W_enc = (const float*)d_in[2];   // [512][512]
  const float* b_enc = (const float*)d_in[3];   // [512]
  const float* W_dec = (const float*)d_in[4];   // [512][512]
  const float* W_out = (const float*)d_in[5];   // [1024][512]
  const float* b_out = (const float*)d_in[6];   // [1024]
  float* out = (float*)d_out;                   // [131072][1024]

  char* ws = (char*)d_ws;
  float* E  = (float*)ws;                  // 2048*512*4 = 4 MB
  float* Dm = (float*)(ws + (4 << 20));    // 512*512*4  = 1 MB
  short* Wf = (short*)(ws + (5 << 20));    // 1024*512*2 = 1 MB

  pack_wout<<<dim3(256), dim3(256), 0, stream>>>(W_out, Wf);
  proj_gemm<<<dim3(32, 8), dim3(256), 0, stream>>>(h_enc, W_enc, b_enc, E, 1);
  proj_gemm<<<dim3(8, 8), dim3(256), 0, stream>>>(h_dec, W_dec, nullptr, Dm, 0);
  joint_main<<<dim3(2048), dim3(256), 0, stream>>>(E, Dm, Wf, b_out, out);
}